// Round 1
// baseline (170.809 us; speedup 1.0000x reference)
//
#include <hip/hip_runtime.h>

#define N_SPIKES 16384
#define N_UNITS  256
#define N_NEIGHB 128
#define RANK     5
#define NC       64
#define NC_OBS   12
#define N_CAND   10
#define DD       60                 // RANK * NC_OBS
#define DD4      15                 // DD / 4
#define OUT_COLS 61
#define OUT_SIZE (N_UNITS * OUT_COLS)   // 15616
#define N_PART   8                  // flush de-contention factor

// ---------------------------------------------------------------------------
// Kernel P: fused nu-gather + matvec.  Lane owns unit u.
//   nu[d] = mu[u, d/12, obs_ix[h, d%12]]   (gathered straight into LDS tile)
//   w     = Coo_inv[h] @ nu                (C rows wave-uniform -> scalarized)
//   b     = log_prop[u] - 0.5 * nu.w
// grid = 256 blocks (2 per h, 128 units), block = 128 (2 waves x 64 lanes)
// ---------------------------------------------------------------------------
__global__ __launch_bounds__(128) void precompute_kernel(
    const float* __restrict__ mu, const float* __restrict__ Coo_inv,
    const int* __restrict__ obs_ix, const float* __restrict__ log_prop,
    float* __restrict__ w_buf, float* __restrict__ b_buf)
{
    __shared__ float tile[128 * 61];   // per-lane nu, stride 61 (odd: conflict-free)

    const int h    = blockIdx.x >> 1;
    const int tid  = threadIdx.x;
    const int lane = tid & 63;
    const int wave = tid >> 6;
    const int u    = (blockIdx.x & 1) * 128 + wave * 64 + lane;
    const int p    = h * N_UNITS + u;

    int so[NC_OBS];
#pragma unroll
    for (int j = 0; j < NC_OBS; ++j) so[j] = obs_ix[h * NC_OBS + j];

    // gather nu directly into the LDS tile (r-major: 12 loads share L1 lines)
    const float* __restrict__ mub = mu + u * (RANK * NC);
    float* tl = &tile[tid * 61];
#pragma unroll
    for (int d = 0; d < DD; ++d) {
        const int r = d / NC_OBS;
        const int j = d - r * NC_OBS;
        tl[d] = mub[r * NC + so[j]];
    }

    float wreg[DD];
#pragma unroll
    for (int d = 0; d < DD; ++d) wreg[d] = 0.f;

    const float* __restrict__ C = Coo_inv + h * DD * DD;
    for (int e = 0; e < DD; ++e) {
        const float nu_e = tl[e];                      // ds_read, per-lane
        const float* __restrict__ Crow = C + e * DD;   // wave-uniform
#pragma unroll
        for (int d = 0; d < DD; ++d)
            wreg[d] = fmaf(Crow[d], nu_e, wreg[d]);
    }

    float q2 = 0.f;
#pragma unroll
    for (int d = 0; d < DD; ++d) q2 += wreg[d] * tl[d];   // static ds_reads

#pragma unroll
    for (int k = 0; k < DD4; ++k) {
        float4 o;
        o.x = wreg[4*k+0]; o.y = wreg[4*k+1];
        o.z = wreg[4*k+2]; o.w = wreg[4*k+3];
        ((float4*)w_buf)[p * DD4 + k] = o;
    }
    b_buf[p] = log_prop[u] - 0.5f * q2;
}

// ---------------------------------------------------------------------------
// Kernel S: per-spike softmax + scatter.  16-lane float4 groups, exactly
// 4 spikes per wave (no outer loop).  512 blocks x 512 thr = 16384 spikes.
// LDS acc 62.5 KB -> 2 blocks/CU = 16 waves/CU resident.  Flush via global
// fire-and-forget atomics into ONE OF 8 pre-zeroed partial buffers
// (blockIdx & 7) -> 8x fewer same-address atomic chains vs single d_out.
// ---------------------------------------------------------------------------
__global__ __launch_bounds__(512, 4) void spike_kernel(
    const float* __restrict__ features, const float* __restrict__ noise_lp,
    const int* __restrict__ cands, const int* __restrict__ nid,
    const float* __restrict__ w_buf, const float* __restrict__ b_buf,
    float* __restrict__ part_base)
{
    __shared__ float acc[OUT_SIZE];
    const int tid = threadIdx.x;
    for (int i = tid; i < OUT_SIZE; i += 512) acc[i] = 0.f;

    float* __restrict__ part = part_base + (blockIdx.x & (N_PART - 1)) * OUT_SIZE;

    const int lane = tid & 63;
    const int wave = tid >> 6;
    const int l = lane & 15;          // dim-chunk within group
    const int s = lane >> 4;          // spike slot within wave
    const bool dimlane = (l < DD4);   // lanes 0..14 hold float4 dims
    const int n = blockIdx.x * 32 + wave * 4 + s;

    // issue all independent loads up front
    const float4* __restrict__ f4 = (const float4*)features;
    const float4* __restrict__ w4 = (const float4*)w_buf;
    const float4 z4 = {0.f, 0.f, 0.f, 0.f};
    const float4 xf = dimlane ? f4[n * DD4 + l] : z4;
    const int h = nid[n];
    const float nlp = noise_lp[0];
    int uc[N_CAND];
#pragma unroll
    for (int c = 0; c < N_CAND; ++c) uc[c] = cands[n * N_CAND + c];

    float4 wv[N_CAND]; float bb[N_CAND];
#pragma unroll
    for (int c = 0; c < N_CAND; ++c) {
        const int p = h * N_UNITS + uc[c];
        wv[c] = dimlane ? w4[p * DD4 + l] : z4;
        bb[c] = b_buf[p];
    }

    float ll[N_CAND];
#pragma unroll
    for (int c = 0; c < N_CAND; ++c) {
        float t = wv[c].x*xf.x + wv[c].y*xf.y + wv[c].z*xf.z + wv[c].w*xf.w;
        t += __shfl_xor(t, 8, 64);
        t += __shfl_xor(t, 4, 64);
        t += __shfl_xor(t, 2, 64);
        t += __shfl_xor(t, 1, 64);
        ll[c] = bb[c] + t;
    }

    float m = nlp;
#pragma unroll
    for (int c = 0; c < N_CAND; ++c) m = fmaxf(m, ll[c]);
    float ssum = __expf(nlp - m);
    float qv[N_CAND];
#pragma unroll
    for (int c = 0; c < N_CAND; ++c) { qv[c] = __expf(ll[c] - m); ssum += qv[c]; }
    const float inv = 1.f / ssum;

    __syncthreads();   // acc zero-init complete

#pragma unroll
    for (int c = 0; c < N_CAND; ++c) {
        const float q = qv[c] * inv;
        const int ub = uc[c] * OUT_COLS;
        if (dimlane) {
            const int a = ub + 1 + l * 4;
            atomicAdd(&acc[a + 0], q * xf.x);
            atomicAdd(&acc[a + 1], q * xf.y);
            atomicAdd(&acc[a + 2], q * xf.z);
            atomicAdd(&acc[a + 3], q * xf.w);
        } else if (l == DD4) {        // one lane per group: count column
            atomicAdd(&acc[ub], q);
        }
    }

    __syncthreads();
    // flush to pre-zeroed partial buffer; skip zeros (saves ~30% of atomics)
    for (int i = tid; i < OUT_SIZE; i += 512) {
        const float v = acc[i];
        if (v != 0.f) atomicAdd(&part[i], v);
    }
}

// ---------------------------------------------------------------------------
// Kernel R: sum the 8 partials into d_out.  61 blocks x 256 = 15616 threads,
// one output element each; fully coalesced, non-atomic.  ~500 KB read.
// ---------------------------------------------------------------------------
__global__ __launch_bounds__(256) void reduce_kernel(
    const float* __restrict__ part, float* __restrict__ out)
{
    const int i = blockIdx.x * 256 + threadIdx.x;   // exact: 61*256 == OUT_SIZE
    float s = part[i];
#pragma unroll
    for (int k = 1; k < N_PART; ++k) s += part[k * OUT_SIZE + i];
    out[i] = s;
}

extern "C" void kernel_launch(void* const* d_in, const int* in_sizes, int n_in,
                              void* d_out, int out_size, void* d_ws, size_t ws_size,
                              hipStream_t stream) {
    const float* features    = (const float*)d_in[0];
    const float* mu          = (const float*)d_in[1];
    const float* Coo_inv     = (const float*)d_in[2];
    // d_in[3] = Coo_logdet : unused (cancels in softmax)
    const float* log_prop    = (const float*)d_in[4];
    const float* noise_lp    = (const float*)d_in[5];
    const int*   cands       = (const int*)d_in[6];
    const int*   nid         = (const int*)d_in[7];
    const int*   obs_ix      = (const int*)d_in[8];
    float* out = (float*)d_out;

    char* ws = (char*)d_ws;
    float* w_buf = (float*)ws;                    // 128*256*60*4 = 7,864,320 B
    float* b_buf = (float*)(ws + 7864320);        // 128*256*4    =   131,072 B
    float* part  = (float*)(ws + 7995392);        // 8*15616*4    =   499,712 B

    hipMemsetAsync(part, 0, (size_t)N_PART * OUT_SIZE * sizeof(float), stream);
    precompute_kernel<<<256, 128, 0, stream>>>(mu, Coo_inv, obs_ix, log_prop,
                                               w_buf, b_buf);
    spike_kernel<<<512, 512, 0, stream>>>(features, noise_lp, cands, nid,
                                          w_buf, b_buf, part);
    reduce_kernel<<<61, 256, 0, stream>>>(part, out);
}